// Round 1
// 114.207 us; speedup vs baseline: 1.0495x; 1.0495x over previous
//
#include <hip/hip_runtime.h>
#include <math.h>

// Problem constants (reference: N=256, S=1, stimulus 144x256, retina 144x256)
#define NB    256
#define IMG_H 144
#define IMG_W 256
#define IMG_ELEMS (IMG_H * IMG_W)   // 36864 floats
#define HR    144
#define WR    256
#define FDIM  16
#define DDIM  128

// LDS image layout: zero-bordered.
//   stored row s = src_row + 1, s in [0,146]; row stride 260 floats (1040 B, 16B aligned)
//   data col c at offset c+4 (offsets 4..259); offset 3 = left zero border (x=-1)
//   offsets 260,261 of a row = offsets 0,1 of next row (right border x=256,257) -> zeroed
//   rows s=0 (y=-1), s=145 (y=144), s=146 (y=145) fully zero; tail group at 147*260
#define STRIDE 260
#define SIMG_FLOATS (147 * STRIDE + 4)   // 38224 floats = 149.3 KiB

#define FOV_HALF_RAD 0.6544984694978736f   // 0.5 * 75deg in rad
#define GELU_GAMMA   1.7015043497085571f
#define OUT_OF_RANGE 10.0f

typedef float f32x4 __attribute__((ext_vector_type(4)));

// jax.nn.gelu default is approximate=True (tanh form)
__device__ __forceinline__ float gelu_gamma(float x) {
    const float k0 = 0.7978845608028654f;  // sqrt(2/pi)
    const float k1 = 0.044715f;
    float t = tanhf(k0 * (x + k1 * x * x * x));
    return 0.5f * x * (1.0f + t) * GELU_GAMMA;
}

// Fully fused: per-image MLP -> rotation matrix -> retina resample.
// One block per image, 1024 threads. Wave 0 runs the MLP (single-wave, no
// block barriers needed) while waves 1..15 stage the image into LDS. d_ws is
// NOT used -> no workspace poison fill in the timed graph, no extra launch.
__global__ void __launch_bounds__(1024, 4) fused_retina_kernel(
    const float* __restrict__ stim,   // [NB, 1, IMG_H, IMG_W]
    const float* __restrict__ persp,  // [NB, FDIM]
    const float* __restrict__ W1,     // [FDIM, DDIM]
    const float* __restrict__ b1,     // [DDIM]
    const float* __restrict__ W2,     // [DDIM, DDIM]
    const float* __restrict__ b2,     // [DDIM]
    const float* __restrict__ Wp,     // [DDIM, 3]
    const float* __restrict__ bp,     // [3]
    float* __restrict__ out)          // [NB, 1, HR, WR]
{
    __shared__ float simg[SIMG_FLOATS];
    __shared__ float sh1[DDIM];
    __shared__ float sh2[DDIM];
    __shared__ float sAng[3];
    __shared__ float sR[9];

    const int tid  = threadIdx.x;
    const int n    = blockIdx.x;
    const int wid  = tid >> 6;
    const int lane = tid & 63;

    const float* __restrict__ img = stim + (size_t)n * IMG_ELEMS;

    // ---- zero the border cells (340 f32x4 groups, disjoint from staged data)
    if (tid < 340) {
        f32x4 z = {0.0f, 0.0f, 0.0f, 0.0f};
        int idx;
        if (tid < 195) {                       // full zero rows s=0,145,146
            const int rr = tid / 65;
            const int g  = tid - rr * 65;      // 0..64 -> offsets 0..259
            const int s  = (rr == 0) ? 0 : (144 + rr);
            idx = s * STRIDE + g * 4;
        } else if (tid < 339) {                // left borders of data rows s=1..144
            idx = (tid - 194) * STRIDE;        // offsets 0..3
        } else {                               // tail cells after row s=146
            idx = 147 * STRIDE;                // 38220..38223
        }
        *(f32x4*)&simg[idx] = z;
    }

    if (wid > 0) {
        // ---- waves 1..15: stage image -> LDS (9216 f32x4 groups over 960 threads)
        const int t = tid - 64;
        const f32x4* __restrict__ src = (const f32x4*)img;
#pragma unroll
        for (int p = 0; p < 10; ++p) {
            const int g = t + p * 960;
            if (g < 9216) {
                const int row = g >> 6;        // 64 groups per image row
                const int c4  = g & 63;
                *(f32x4*)&simg[(row + 1) * STRIDE + 4 + c4 * 4] = src[g];
            }
        }
    } else {
        // ---- wave 0: the whole MLP, single-wave (lgkmcnt orders LDS within wave)
        float a0 = b1[lane], a1 = b1[lane + 64];
#pragma unroll
        for (int f = 0; f < FDIM; ++f) {
            const float p = persp[n * FDIM + f];
            a0 = fmaf(p, W1[f * DDIM + lane],      a0);
            a1 = fmaf(p, W1[f * DDIM + lane + 64], a1);
        }
        sh1[lane]      = gelu_gamma(a0);
        sh1[lane + 64] = gelu_gamma(a1);
        asm volatile("s_waitcnt lgkmcnt(0)" ::: "memory");

        float c0 = b2[lane], c1 = b2[lane + 64];
#pragma unroll 8
        for (int k = 0; k < DDIM; ++k) {
            const float s = sh1[k];
            c0 = fmaf(s, W2[k * DDIM + lane],      c0);
            c1 = fmaf(s, W2[k * DDIM + lane + 64], c1);
        }
        sh2[lane]      = gelu_gamma(c0);
        sh2[lane + 64] = gelu_gamma(c1);
        asm volatile("s_waitcnt lgkmcnt(0)" ::: "memory");

        if (lane < 3) {
            float a = bp[lane];
#pragma unroll 8
            for (int k = 0; k < DDIM; ++k)
                a = fmaf(sh2[k], Wp[k * 3 + lane], a);
            sAng[lane] = a;
        }
        asm volatile("s_waitcnt lgkmcnt(0)" ::: "memory");

        if (lane == 0) {
            const float cx = cosf(sAng[0]), sx = sinf(sAng[0]);
            const float cy = cosf(sAng[1]), sy = sinf(sAng[1]);
            const float cz = cosf(sAng[2]), sz = sinf(sAng[2]);
            sR[0] = cz * cy;  sR[1] = cz * sy * sx - sz * cx;  sR[2] = cz * sy * cx + sz * sx;
            sR[3] = sz * cy;  sR[4] = sz * sy * sx + cz * cx;  sR[5] = sz * sy * cx - cz * sx;
            sR[6] = -sy;      sR[7] = cy * sx;                 sR[8] = cy * cx;
        }
    }
    __syncthreads();

    // block-uniform rotation (LDS broadcast reads, conflict-free)
    const float r0 = sR[0], r1 = sR[1], r2 = sR[2];
    const float r3 = sR[3], r4 = sR[4], r5 = sR[5];
    const float r6 = sR[6], r7 = sR[7], r8 = sR[8];

    float* __restrict__ outn = out + (size_t)n * IMG_ELEMS;

    // ---- gather: lane-adjacent pixels (source lane-stride ~1 dword -> ~no
    // bank conflicts); zero border removes all masks/clamps; v00/v01 and
    // v10/v11 adjacent -> ds_read2_b32 pairs
#pragma unroll 4
    for (int it = 0; it < 36; ++it) {
        const int px0 = it * 1024 + tid;
        const int h   = px0 >> 8;
        const int w   = px0 & 255;

        const float gx  = ((float)(2 * w + 1) - 256.0f) * (1.0f / 256.0f);
        const float gy  = ((float)(2 * h + 1) - 144.0f) * (1.0f / 256.0f);
        const float axv = gx * FOV_HALF_RAD;
        const float ayv = gy * FOV_HALF_RAD;
        const float tt  = fmaf(axv, axv, ayv * ayv);   // a^2 <= 0.56

        // sinc(a): even Taylor in t, |err| ~1e-8 on this range
        float sc = fmaf(tt, 2.7557319e-6f, -1.9841270e-4f);
        sc = fmaf(tt, sc,  8.3333333e-3f);
        sc = fmaf(tt, sc, -1.6666667e-1f);
        sc = fmaf(tt, sc,  1.0f);

        // cos(a): even Taylor in t
        float ca = fmaf(tt, 2.4801587e-5f, -1.3888889e-3f);
        ca = fmaf(tt, ca,  4.1666667e-2f);
        ca = fmaf(tt, ca, -0.5f);
        ca = fmaf(tt, ca,  1.0f);

        const float dx = sc * axv, dy = sc * ayv, dz = ca;

        const float rx = fmaf(r0, dx, fmaf(r1, dy, r2 * dz));
        const float ry = fmaf(r3, dx, fmaf(r4, dy, r5 * dz));
        const float rz = fmaf(r6, dx, fmaf(r7, dy, r8 * dz));

        const float inv  = __builtin_amdgcn_rcpf(rz);
        const bool  safe = rz > 0.001f;
        const float gxp  = safe ? rx * inv : OUT_OF_RANGE;
        const float gyp  = safe ? ry * inv : OUT_OF_RANGE;

        float pxf = fmaf(gxp, 256.0f, (float)(IMG_W - 1)) * 0.5f;
        float pyf = fmaf(gyp, 256.0f, (float)(IMG_H - 1)) * 0.5f;
        // clamp onto the zero border: out-of-range lands on zero cells with
        // zero fractional weight -> exact per-corner mask semantics
        pxf = fminf(fmaxf(pxf, -1.0f), 256.0f);
        pyf = fminf(fmaxf(pyf, -1.0f), 144.0f);

        const float x0f = floorf(pxf), y0f = floorf(pyf);
        const float wx  = pxf - x0f,   wy  = pyf - y0f;
        const int   xi  = (int)x0f,    yi  = (int)y0f;   // xi in [-1,256], yi in [-1,144]

        const int a00 = (yi + 1) * STRIDE + xi + 4;
        const int a10 = a00 + STRIDE;

        const float v00 = simg[a00];
        const float v01 = simg[a00 + 1];
        const float v10 = simg[a10];
        const float v11 = simg[a10 + 1];

        const float top = fmaf(wx, v01 - v00, v00);
        const float bot = fmaf(wx, v11 - v10, v10);
        const float res = fmaf(wy, bot - top, top);

        __builtin_nontemporal_store(res, outn + px0);
    }
}

extern "C" void kernel_launch(void* const* d_in, const int* in_sizes, int n_in,
                              void* d_out, int out_size, void* d_ws, size_t ws_size,
                              hipStream_t stream) {
    const float* stimulus    = (const float*)d_in[0]; // [256,1,144,256]
    const float* perspective = (const float*)d_in[1]; // [256,16]
    const float* W1          = (const float*)d_in[2]; // [16,128]
    const float* b1          = (const float*)d_in[3]; // [128]
    const float* W2          = (const float*)d_in[4]; // [128,128]
    const float* b2          = (const float*)d_in[5]; // [128]
    const float* Wp          = (const float*)d_in[6]; // [128,3]
    const float* bp          = (const float*)d_in[7]; // [3]
    float* out = (float*)d_out;

    (void)d_ws; (void)ws_size;  // intentionally unused: no workspace -> no re-poison fill

    fused_retina_kernel<<<NB, 1024, 0, stream>>>(
        stimulus, perspective, W1, b1, W2, b2, Wp, bp, out);
}